// Round 1
// 191.670 us; speedup vs baseline: 1.0113x; 1.0113x over previous
//
#include <hip/hip_runtime.h>

typedef unsigned short u16;
typedef unsigned int u32;
typedef __attribute__((ext_vector_type(8))) short short8;
typedef __attribute__((ext_vector_type(4))) float floatx4;
typedef __attribute__((ext_vector_type(4))) float float4v;

#define B_ 32
#define T_ 168
#define NH_ 32
#define NM_ 64
#define E_ 384
#define HL_ 128
#define FUT_ 24
#define SLOPE_ 0.01f
#define XP_ 80     // xbuf stride per batch (u16)
#define HP_ 144    // hbuf stride per batch (u16)
#define WIH_LP 72  // Wih staging row stride (u16): 512*72 = 36864 u16 fits ovl
#define WHH_LP 136 // Whh staging row stride (u16): 256*136 = 34816 u16 fits ovl
#define OVL_E (T_ * 4 * XP_)  // 53760 u16 = 107.5 KB

// gate scales folded into the staged weights/bias:
//   sigm(x) = rcp(1 + exp2(-log2e * x))  -> rows i,f,o pre-scaled by -log2e
//   tanh(x) = 1 - 2*rcp(1 + exp2(2*log2e * x)) -> rows g pre-scaled by +2*log2e
#define NS1_ (-1.4426950408889634f)
#define S2_ (2.8853900817779268f)

static __device__ __forceinline__ float b2f(u16 u) {
  u32 v = ((u32)u) << 16;
  return __builtin_bit_cast(float, v);
}
static __device__ __forceinline__ u16 f2bf(float f) {
  u32 x = __builtin_bit_cast(u32, f);
  u32 r = (x + 0x7fffu + ((x >> 16) & 1u)) >> 16;
  return (u16)r;
}
static __device__ __forceinline__ float fexp2(float x) { return __builtin_amdgcn_exp2f(x); }
static __device__ __forceinline__ float frcp(float x) { return __builtin_amdgcn_rcpf(x); }
static __device__ __forceinline__ float sel4(floatx4 v, int r) {
  float m0 = (r & 1) ? v[1] : v[0];
  float m1 = (r & 1) ? v[3] : v[2];
  return (r & 2) ? m1 : m0;
}
static __device__ __forceinline__ float lrelu(float x) { return fmaxf(x, SLOPE_ * x); }

// Fully fused GNN + per-station LSTM + head.
// Grid: 256 WGs = 32 stations x 8 batch-groups (4 batches). 512 thr = 8 waves.
__launch_bounds__(512, 2)
__global__ void fused_kernel(const float* __restrict__ dm, const float* __restrict__ dh,
                             const int* __restrict__ eidx,
                             const float* __restrict__ Wroot, const float* __restrict__ Wrel,
                             const float* __restrict__ bgnn,
                             const float* __restrict__ Wih, const float* __restrict__ Whh,
                             const float* __restrict__ bih, const float* __restrict__ bhh,
                             const float* __restrict__ Wlin, const float* __restrict__ blin,
                             float* __restrict__ out) {
  const int s = blockIdx.x & 31;
  const int bg = blockIdx.x >> 5;
  const int tid = threadIdx.x;
  const int w = tid >> 6;
  const int lane = tid & 63;
  const int cm = lane & 15;
  const int q = lane >> 4;
  const int b = cm & 3;
  const int rho = cm >> 2;

  // ovl: weight staging rounds first, then xbuf (GNN features)
  __shared__ __align__(16) u16 ovl[OVL_E];
  __shared__ __align__(16) u16 hbuf[2 * 4 * HP_];
  __shared__ float xh_lds[4][T_];
  __shared__ float ag_lds[4][T_];
  __shared__ float wr_s[64], wv_s[64], bg_s[64];
  __shared__ int srcs[E_];
  __shared__ int nsrc, iflag;

  // ---- A: init
  if (tid == 0) { nsrc = 0; iflag = 0; }
  for (int i = tid; i < 2 * 4 * HP_; i += 512) hbuf[i] = 0;
  __syncthreads();

  // ---- B: int64-vs-int32 edge_index probe
  {
    int odd = 0;
    for (int e = tid; e < E_; e += 512) odd |= eidx[2 * e + 1];
    if (odd) atomicOr(&iflag, 1);
  }
  __syncthreads();
  const bool i32 = iflag != 0;

  // ---- C: in-edges for this station; stage small tensors; bias (pre-scaled)
  for (int e = tid; e < E_; e += 512) {
    int se = i32 ? eidx[e] : eidx[2 * e];
    int de = i32 ? eidx[E_ + e] : eidx[2 * E_ + 2 * e];
    if (de == s) { int i = atomicAdd(&nsrc, 1); srcs[i] = se; }
  }
  if (tid < 64) { wr_s[tid] = Wroot[tid]; wv_s[tid] = Wrel[tid]; bg_s[tid] = bgnn[tid]; }
  for (int i = tid; i < 4 * T_; i += 512) {
    int bb = i / T_, t = i % T_;
    xh_lds[bb][t] = dh[((size_t)(bg * 4 + bb) * T_ + t) * NH_ + s];
  }
  floatx4 bias_init[4];
#pragma unroll
  for (int blk = 0; blk < 4; blk++) {
    const float scb = (blk == 2) ? S2_ : NS1_;
#pragma unroll
    for (int r = 0; r < 4; r++) {
      const int nb = blk * 128 + w * 16 + q * 4 + r;
      bias_init[blk][r] = (bih[s * 512 + nb] + bhh[s * 512 + nb]) * scb;
    }
  }
  __syncthreads();

  // ---- D: per-(b,t) graph aggregation (avg ~4 in-edges/station)
  const int ns = nsrc;
  for (int i = tid; i < 4 * T_; i += 512) {
    int bb = i / T_, t = i % T_;
    size_t gb = (size_t)(bg * 4 + bb) * T_ + t;
    float a = 0.f;
    for (int j = 0; j < ns; j++) {
      int sr = srcs[j];
      a += (sr < NH_) ? dh[gb * NH_ + sr] : dm[gb * NM_ + (sr - NH_)];
    }
    ag_lds[bb][t] = a;
  }

  // ---- W: coalesced LDS-staged weight load, THREE fully-unrolled rounds.
  // Gate-scale constants are folded in here (off the recurrent critical path).
  short8 Af[4][6];
  const int nl = w * 16 + cm;  // this lane's gate-row within a 128-block
  // Round 1: all of Wih (512 rows x 64); row = j>>4, gate block = j>>11
  __syncthreads();
  {
    const float* g = Wih + (size_t)s * 512 * 64;
#pragma unroll
    for (int it = 0; it < 16; it++) {
      int j = tid + it * 512;
      float4v v = *(const float4v*)(g + 4 * j);
      const float sc = ((j >> 11) == 2) ? S2_ : NS1_;
      u16* dst = ovl + (j >> 4) * WIH_LP + (j & 15) * 4;
      dst[0] = f2bf(v[0] * sc); dst[1] = f2bf(v[1] * sc);
      dst[2] = f2bf(v[2] * sc); dst[3] = f2bf(v[3] * sc);
    }
  }
  __syncthreads();
#pragma unroll
  for (int blk = 0; blk < 4; blk++)
#pragma unroll
    for (int kk = 0; kk < 2; kk++)
      Af[blk][kk] = *(const short8*)(ovl + (blk * 128 + nl) * WIH_LP + kk * 32 + q * 8);
  __syncthreads();
  // Round 2: Whh rows 0..255 (gate blocks 0,1 -> always -log2e)
  {
    const float* g = Whh + (size_t)s * 512 * 128;
#pragma unroll
    for (int it = 0; it < 16; it++) {
      int j = tid + it * 512;
      float4v v = *(const float4v*)(g + 4 * j);
      u16* dst = ovl + (j >> 5) * WHH_LP + (j & 31) * 4;
      dst[0] = f2bf(v[0] * NS1_); dst[1] = f2bf(v[1] * NS1_);
      dst[2] = f2bf(v[2] * NS1_); dst[3] = f2bf(v[3] * NS1_);
    }
  }
  __syncthreads();
#pragma unroll
  for (int blk = 0; blk < 2; blk++)
#pragma unroll
    for (int kk = 0; kk < 4; kk++)
      Af[blk][2 + kk] = *(const short8*)(ovl + (blk * 128 + nl) * WHH_LP + kk * 32 + q * 8);
  __syncthreads();
  // Round 3: Whh rows 256..511 (block 2 = g -> +2log2e for j<4096, block 3 = o -> -log2e)
  {
    const float* g = Whh + ((size_t)s * 512 + 256) * 128;
#pragma unroll
    for (int it = 0; it < 16; it++) {
      int j = tid + it * 512;
      float4v v = *(const float4v*)(g + 4 * j);
      const float sc = (j < 4096) ? S2_ : NS1_;
      u16* dst = ovl + (j >> 5) * WHH_LP + (j & 31) * 4;
      dst[0] = f2bf(v[0] * sc); dst[1] = f2bf(v[1] * sc);
      dst[2] = f2bf(v[2] * sc); dst[3] = f2bf(v[3] * sc);
    }
  }
  __syncthreads();
#pragma unroll
  for (int blk = 2; blk < 4; blk++)
#pragma unroll
    for (int kk = 0; kk < 4; kk++)
      Af[blk][2 + kk] = *(const short8*)(ovl + ((blk - 2) * 128 + nl) * WHH_LP + kk * 32 + q * 8);
  __syncthreads();

  // ---- E: precompute GNN features into xbuf (= ovl; weights now in registers)
  {
    const int k = tid & 63;
    const int bb = (tid >> 6) & 3;
    const int th = tid >> 8;
    const float wrk = wr_s[k], wvk = wv_s[k], bgk = bg_s[k];
    for (int i = 0; i < T_ / 2; i++) {
      const int t = th * (T_ / 2) + i;
      const float xv = xh_lds[bb][t] * wrk + ag_lds[bb][t] * wvk + bgk;
      ovl[t * (4 * XP_) + bb * XP_ + k] = f2bf(lrelu(xv));
    }
  }
  __syncthreads();

  // ---- recurrent loop. Phase-overlapped schedule per step:
  //   [ds_read Bh + Bx(t+1)] -> [8 MFMA: g,i chains] -> [extract g,i + exp2]
  //   -> [8 MFMA: f,o chains] -> [8 MFMA: x-part(t+1)] -> [activation tail]
  // so transcendental/VALU work hides under MFMA pipe occupancy.
  floatx4 accN[4];
  {
    short8 Bx0 = *(const short8*)(ovl + b * XP_ + q * 8);
    short8 Bx1 = *(const short8*)(ovl + b * XP_ + 32 + q * 8);
#pragma unroll
    for (int blk = 0; blk < 4; blk++) {
      accN[blk] = __builtin_amdgcn_mfma_f32_16x16x32_bf16(Af[blk][0], Bx0, bias_init[blk], 0, 0, 0);
      accN[blk] = __builtin_amdgcn_mfma_f32_16x16x32_bf16(Af[blk][1], Bx1, accN[blk], 0, 0, 0);
    }
  }
  float c = 0.0f;
#pragma unroll 2
  for (int t = 0; t < T_; t++) {
    const int p = t & 1, pn = p ^ 1;
    short8 Bh[4];
#pragma unroll
    for (int kk = 0; kk < 4; kk++)
      Bh[kk] = *(const short8*)(hbuf + p * (4 * HP_) + b * HP_ + kk * 32 + q * 8);
    short8 Bx0n, Bx1n;
    const bool more = (t + 1 < T_);
    if (more) {
      Bx0n = *(const short8*)(ovl + (t + 1) * (4 * XP_) + b * XP_ + q * 8);
      Bx1n = *(const short8*)(ovl + (t + 1) * (4 * XP_) + b * XP_ + 32 + q * 8);
    }

    // g (blk2) and i (blk0) chains first -> their transcendentals start early
    floatx4 a2 = accN[2], a0 = accN[0];
#pragma unroll
    for (int kk = 0; kk < 4; kk++) {
      a2 = __builtin_amdgcn_mfma_f32_16x16x32_bf16(Af[2][2 + kk], Bh[kk], a2, 0, 0, 0);
      a0 = __builtin_amdgcn_mfma_f32_16x16x32_bf16(Af[0][2 + kk], Bh[kk], a0, 0, 0, 0);
    }
    const float gg = sel4(a2, rho);   // = 2*log2e * g
    const float gi = sel4(a0, rho);   // = -log2e * i
    const float Eg = fexp2(gg);
    const float Ei = fexp2(gi);

    // f (blk1) and o (blk3) chains
    floatx4 a1 = accN[1], a3 = accN[3];
#pragma unroll
    for (int kk = 0; kk < 4; kk++) {
      a1 = __builtin_amdgcn_mfma_f32_16x16x32_bf16(Af[1][2 + kk], Bh[kk], a1, 0, 0, 0);
      a3 = __builtin_amdgcn_mfma_f32_16x16x32_bf16(Af[3][2 + kk], Bh[kk], a3, 0, 0, 0);
    }
    // x-part + bias for step t+1: independent of everything below, fills MFMA
    // pipe while the activation tail runs on VALU/trans.
    if (more) {
#pragma unroll
      for (int blk = 0; blk < 4; blk++) {
        accN[blk] = __builtin_amdgcn_mfma_f32_16x16x32_bf16(Af[blk][0], Bx0n, bias_init[blk], 0, 0, 0);
        accN[blk] = __builtin_amdgcn_mfma_f32_16x16x32_bf16(Af[blk][1], Bx1n, accN[blk], 0, 0, 0);
      }
    }

    const float tg = 1.0f - 2.0f * frcp(1.0f + Eg);
    const float si = frcp(1.0f + Ei);
    const float gf = sel4(a1, rho);   // = -log2e * f
    const float go = sel4(a3, rho);   // = -log2e * o
    const float sf = frcp(1.0f + fexp2(gf));
    c = sf * c + si * tg;
    const float tc = 1.0f - 2.0f * frcp(1.0f + fexp2(S2_ * c));
    const float so = frcp(1.0f + fexp2(go));
    const float hh = so * tc;
    u32 pk;
    asm("v_cvt_pk_bf16_f32 %0, %1, %2" : "=v"(pk) : "v"(hh), "v"(hh));
    hbuf[pn * (4 * HP_) + b * HP_ + w * 16 + q * 4 + rho] = (u16)pk;
    __syncthreads();
  }

  // ---- head: final h is in hbuf[0]
  if (tid < 4 * FUT_) {
    const int bb = tid / FUT_;
    const int f = tid % FUT_;
    float a = blin[f];
#pragma unroll 8
    for (int k = 0; k < HL_; k++) a += b2f(hbuf[bb * HP_ + k]) * Wlin[f * HL_ + k];
    out[((size_t)(bg * 4 + bb) * NH_ + s) * FUT_ + f] = lrelu(a);
  }
}

extern "C" void kernel_launch(void* const* d_in, const int* in_sizes, int n_in,
                              void* d_out, int out_size, void* d_ws, size_t ws_size,
                              hipStream_t stream) {
  const float* dm = (const float*)d_in[0];
  const float* dh = (const float*)d_in[1];
  const int* eidx = (const int*)d_in[2];
  const float* Wroot = (const float*)d_in[3];
  const float* Wrel = (const float*)d_in[4];
  const float* bgnn = (const float*)d_in[5];
  const float* Wih = (const float*)d_in[6];
  const float* Whh = (const float*)d_in[7];
  const float* bih = (const float*)d_in[8];
  const float* bhh = (const float*)d_in[9];
  const float* Wlin = (const float*)d_in[10];
  const float* blin = (const float*)d_in[11];
  float* out = (float*)d_out;

  fused_kernel<<<256, 512, 0, stream>>>(dm, dh, eidx, Wroot, Wrel, bgnn, Wih, Whh,
                                        bih, bhh, Wlin, blin, out);
}

// Round 2
// 179.716 us; speedup vs baseline: 1.0785x; 1.0665x over previous
//
#include <hip/hip_runtime.h>

typedef unsigned short u16;
typedef unsigned int u32;
typedef __attribute__((ext_vector_type(8))) short short8;
typedef __attribute__((ext_vector_type(4))) float floatx4;
typedef __attribute__((ext_vector_type(4))) float float4v;

#define B_ 32
#define T_ 168
#define NH_ 32
#define NM_ 64
#define E_ 384
#define HL_ 128
#define FUT_ 24
#define SLOPE_ 0.01f
#define XP_ 80     // xbuf stride per batch (u16)
#define HP_ 144    // hbuf stride per batch (u16)
#define WIH_LP 72  // Wih staging row stride (u16): 512*72 = 36864 u16 fits ovl
#define WHH_LP 136 // Whh staging row stride (u16): 256*136 = 34816 u16 fits ovl
#define OVL_E (T_ * 4 * XP_)  // 53760 u16 = 107.5 KB
// xg: per-wave x-part gate staging. [w][tph][b][q][r][blk] strides (floats):
#define XG_B 68    // b stride (64 + 4 pad, keeps 16B alignment, spreads banks)
#define XG_T (4 * XG_B)   // 272
#define XG_W (4 * XG_T)   // 1088

// gate scales folded into the staged weights/bias:
//   sigm(x) = rcp(1 + exp2(-log2e * x))  -> rows i,f,o pre-scaled by -log2e
//   tanh(x) = 1 - 2*rcp(1 + exp2(2*log2e * x)) -> rows g pre-scaled by +2*log2e
#define NS1_ (-1.4426950408889634f)
#define S2_ (2.8853900817779268f)

static __device__ __forceinline__ float b2f(u16 u) {
  u32 v = ((u32)u) << 16;
  return __builtin_bit_cast(float, v);
}
static __device__ __forceinline__ u16 f2bf(float f) {
  u32 x = __builtin_bit_cast(u32, f);
  u32 r = (x + 0x7fffu + ((x >> 16) & 1u)) >> 16;
  return (u16)r;
}
static __device__ __forceinline__ float fexp2(float x) { return __builtin_amdgcn_exp2f(x); }
static __device__ __forceinline__ float frcp(float x) { return __builtin_amdgcn_rcpf(x); }
static __device__ __forceinline__ float sel4(floatx4 v, int r) {
  float m0 = (r & 1) ? v[1] : v[0];
  float m1 = (r & 1) ? v[3] : v[2];
  return (r & 2) ? m1 : m0;
}
static __device__ __forceinline__ float lrelu(float x) { return fmaxf(x, SLOPE_ * x); }

// Fully fused GNN + per-station LSTM + head.
// Grid: 256 WGs = 32 stations x 8 batch-groups (4 batches). 512 thr = 8 waves.
__launch_bounds__(512, 2)
__global__ void fused_kernel(const float* __restrict__ dm, const float* __restrict__ dh,
                             const int* __restrict__ eidx,
                             const float* __restrict__ Wroot, const float* __restrict__ Wrel,
                             const float* __restrict__ bgnn,
                             const float* __restrict__ Wih, const float* __restrict__ Whh,
                             const float* __restrict__ bih, const float* __restrict__ bhh,
                             const float* __restrict__ Wlin, const float* __restrict__ blin,
                             float* __restrict__ out) {
  const int s = blockIdx.x & 31;
  const int bg = blockIdx.x >> 5;
  const int tid = threadIdx.x;
  const int w = tid >> 6;
  const int lane = tid & 63;
  const int cm = lane & 15;
  const int q = lane >> 4;
  const int b = cm & 3;
  const int rho = cm >> 2;

  // ovl: weight staging rounds first, then xbuf (GNN features)
  __shared__ __align__(16) u16 ovl[OVL_E];
  __shared__ __align__(16) u16 hbuf[2 * 4 * HP_];
  __shared__ __align__(16) float xgbuf[8 * XG_W];  // 34816 B, wave-private slices
  __shared__ float xh_lds[4][T_];
  __shared__ float ag_lds[4][T_];
  __shared__ float wr_s[64], wv_s[64], bg_s[64];
  __shared__ int srcs[E_];
  __shared__ int nsrc, iflag;

  // ---- A: init
  if (tid == 0) { nsrc = 0; iflag = 0; }
  for (int i = tid; i < 2 * 4 * HP_; i += 512) hbuf[i] = 0;
  __syncthreads();

  // ---- B: int64-vs-int32 edge_index probe
  {
    int odd = 0;
    for (int e = tid; e < E_; e += 512) odd |= eidx[2 * e + 1];
    if (odd) atomicOr(&iflag, 1);
  }
  __syncthreads();
  const bool i32 = iflag != 0;

  // ---- C: in-edges for this station; stage small tensors; bias (pre-scaled)
  for (int e = tid; e < E_; e += 512) {
    int se = i32 ? eidx[e] : eidx[2 * e];
    int de = i32 ? eidx[E_ + e] : eidx[2 * E_ + 2 * e];
    if (de == s) { int i = atomicAdd(&nsrc, 1); srcs[i] = se; }
  }
  if (tid < 64) { wr_s[tid] = Wroot[tid]; wv_s[tid] = Wrel[tid]; bg_s[tid] = bgnn[tid]; }
  for (int i = tid; i < 4 * T_; i += 512) {
    int bb = i / T_, t = i % T_;
    xh_lds[bb][t] = dh[((size_t)(bg * 4 + bb) * T_ + t) * NH_ + s];
  }
  floatx4 bias_init[4];
#pragma unroll
  for (int blk = 0; blk < 4; blk++) {
    const float scb = (blk == 2) ? S2_ : NS1_;
#pragma unroll
    for (int r = 0; r < 4; r++) {
      const int nb = blk * 128 + w * 16 + q * 4 + r;
      bias_init[blk][r] = (bih[s * 512 + nb] + bhh[s * 512 + nb]) * scb;
    }
  }
  __syncthreads();

  // ---- D: per-(b,t) graph aggregation (avg ~4 in-edges/station)
  const int ns = nsrc;
  for (int i = tid; i < 4 * T_; i += 512) {
    int bb = i / T_, t = i % T_;
    size_t gb = (size_t)(bg * 4 + bb) * T_ + t;
    float a = 0.f;
    for (int j = 0; j < ns; j++) {
      int sr = srcs[j];
      a += (sr < NH_) ? dh[gb * NH_ + sr] : dm[gb * NM_ + (sr - NH_)];
    }
    ag_lds[bb][t] = a;
  }

  // ---- W: coalesced LDS-staged weight load, THREE fully-unrolled rounds.
  // Gate-scale constants are folded in here (off the recurrent critical path).
  short8 Af[4][6];
  const int nl = w * 16 + cm;  // this lane's gate-row within a 128-block
  // Round 1: all of Wih (512 rows x 64); row = j>>4, gate block = j>>11
  __syncthreads();
  {
    const float* g = Wih + (size_t)s * 512 * 64;
#pragma unroll
    for (int it = 0; it < 16; it++) {
      int j = tid + it * 512;
      float4v v = *(const float4v*)(g + 4 * j);
      const float sc = ((j >> 11) == 2) ? S2_ : NS1_;
      u16* dst = ovl + (j >> 4) * WIH_LP + (j & 15) * 4;
      dst[0] = f2bf(v[0] * sc); dst[1] = f2bf(v[1] * sc);
      dst[2] = f2bf(v[2] * sc); dst[3] = f2bf(v[3] * sc);
    }
  }
  __syncthreads();
#pragma unroll
  for (int blk = 0; blk < 4; blk++)
#pragma unroll
    for (int kk = 0; kk < 2; kk++)
      Af[blk][kk] = *(const short8*)(ovl + (blk * 128 + nl) * WIH_LP + kk * 32 + q * 8);
  __syncthreads();
  // Round 2: Whh rows 0..255 (gate blocks 0,1 -> always -log2e)
  {
    const float* g = Whh + (size_t)s * 512 * 128;
#pragma unroll
    for (int it = 0; it < 16; it++) {
      int j = tid + it * 512;
      float4v v = *(const float4v*)(g + 4 * j);
      u16* dst = ovl + (j >> 5) * WHH_LP + (j & 31) * 4;
      dst[0] = f2bf(v[0] * NS1_); dst[1] = f2bf(v[1] * NS1_);
      dst[2] = f2bf(v[2] * NS1_); dst[3] = f2bf(v[3] * NS1_);
    }
  }
  __syncthreads();
#pragma unroll
  for (int blk = 0; blk < 2; blk++)
#pragma unroll
    for (int kk = 0; kk < 4; kk++)
      Af[blk][2 + kk] = *(const short8*)(ovl + (blk * 128 + nl) * WHH_LP + kk * 32 + q * 8);
  __syncthreads();
  // Round 3: Whh rows 256..511 (block 2 = g -> +2log2e for j<4096, block 3 = o -> -log2e)
  {
    const float* g = Whh + ((size_t)s * 512 + 256) * 128;
#pragma unroll
    for (int it = 0; it < 16; it++) {
      int j = tid + it * 512;
      float4v v = *(const float4v*)(g + 4 * j);
      const float sc = (j < 4096) ? S2_ : NS1_;
      u16* dst = ovl + (j >> 5) * WHH_LP + (j & 31) * 4;
      dst[0] = f2bf(v[0] * sc); dst[1] = f2bf(v[1] * sc);
      dst[2] = f2bf(v[2] * sc); dst[3] = f2bf(v[3] * sc);
    }
  }
  __syncthreads();
#pragma unroll
  for (int blk = 2; blk < 4; blk++)
#pragma unroll
    for (int kk = 0; kk < 4; kk++)
      Af[blk][2 + kk] = *(const short8*)(ovl + ((blk - 2) * 128 + nl) * WHH_LP + kk * 32 + q * 8);
  __syncthreads();

  // ---- E: precompute GNN features into xbuf (= ovl; weights now in registers)
  {
    const int k = tid & 63;
    const int bb = (tid >> 6) & 3;
    const int th = tid >> 8;
    const float wrk = wr_s[k], wvk = wv_s[k], bgk = bg_s[k];
    for (int i = 0; i < T_ / 2; i++) {
      const int t = th * (T_ / 2) + i;
      const float xv = xh_lds[bb][t] * wrk + ag_lds[bb][t] * wvk + bgk;
      ovl[t * (4 * XP_) + bb * XP_ + k] = f2bf(lrelu(xv));
    }
  }
  __syncthreads();

  // ---- recurrent loop.
  // x-part burst: every 4 steps, ONE MFMA set with cols = (b, t-phase) computes
  // the x-gates+bias for 4 timesteps (8 MFMAs instead of 32) -> per-step MFMA
  // count drops 24 -> 18 per wave. Results staged in a wave-private LDS slice
  // (no barrier needed), consumed as one ds_read_b128 per step; h-MFMA chains
  // start from a hoisted zero C and the x-part is added post-extraction.
  floatx4 zvec;
  zvec[0] = 0.f; zvec[1] = 0.f; zvec[2] = 0.f; zvec[3] = 0.f;
  float* const xgw = xgbuf + w * XG_W + rho * XG_T + b * XG_B + q * 16;  // producer (tph=rho)
  const float* const xgr = xgbuf + w * XG_W + b * XG_B + q * 16 + rho * 4;  // consumer base

  float c = 0.0f;
  for (int tt = 0; tt < T_ / 4; tt++) {
    // ---- burst: x-gates for steps tt*4 .. tt*4+3 (cols = (b, tph))
    {
      const int tb = tt * 4 + rho;  // this lane's column carries timestep tb
      short8 Bx0 = *(const short8*)(ovl + tb * (4 * XP_) + b * XP_ + q * 8);
      short8 Bx1 = *(const short8*)(ovl + tb * (4 * XP_) + b * XP_ + 32 + q * 8);
      floatx4 ax[4];
#pragma unroll
      for (int blk = 0; blk < 4; blk++) {
        ax[blk] = __builtin_amdgcn_mfma_f32_16x16x32_bf16(Af[blk][0], Bx0, bias_init[blk], 0, 0, 0);
        ax[blk] = __builtin_amdgcn_mfma_f32_16x16x32_bf16(Af[blk][1], Bx1, ax[blk], 0, 0, 0);
      }
#pragma unroll
      for (int r = 0; r < 4; r++) {
        floatx4 vv;
        vv[0] = ax[0][r]; vv[1] = ax[1][r]; vv[2] = ax[2][r]; vv[3] = ax[3][r];
        *(floatx4*)(xgw + r * 4) = vv;
      }
    }

#pragma unroll
    for (int u = 0; u < 4; u++) {
      const int p = u & 1, pn = p ^ 1;
      short8 Bh[4];
#pragma unroll
      for (int kk = 0; kk < 4; kk++)
        Bh[kk] = *(const short8*)(hbuf + p * (4 * HP_) + b * HP_ + kk * 32 + q * 8);
      // this lane's x+bias gate values for step tt*4+u (blk 0..3)
      const floatx4 xgv = *(const floatx4*)(xgr + u * XG_T);

      // g (blk2) and i (blk0) chains first -> their transcendentals start early
      floatx4 a2 = __builtin_amdgcn_mfma_f32_16x16x32_bf16(Af[2][2], Bh[0], zvec, 0, 0, 0);
      floatx4 a0 = __builtin_amdgcn_mfma_f32_16x16x32_bf16(Af[0][2], Bh[0], zvec, 0, 0, 0);
#pragma unroll
      for (int kk = 1; kk < 4; kk++) {
        a2 = __builtin_amdgcn_mfma_f32_16x16x32_bf16(Af[2][2 + kk], Bh[kk], a2, 0, 0, 0);
        a0 = __builtin_amdgcn_mfma_f32_16x16x32_bf16(Af[0][2 + kk], Bh[kk], a0, 0, 0, 0);
      }
      const float gg = sel4(a2, rho) + xgv[2];  // = 2*log2e * g
      const float gi = sel4(a0, rho) + xgv[0];  // = -log2e * i
      const float Eg = fexp2(gg);
      const float Ei = fexp2(gi);

      // f (blk1) and o (blk3) chains
      floatx4 a1 = __builtin_amdgcn_mfma_f32_16x16x32_bf16(Af[1][2], Bh[0], zvec, 0, 0, 0);
      floatx4 a3 = __builtin_amdgcn_mfma_f32_16x16x32_bf16(Af[3][2], Bh[0], zvec, 0, 0, 0);
#pragma unroll
      for (int kk = 1; kk < 4; kk++) {
        a1 = __builtin_amdgcn_mfma_f32_16x16x32_bf16(Af[1][2 + kk], Bh[kk], a1, 0, 0, 0);
        a3 = __builtin_amdgcn_mfma_f32_16x16x32_bf16(Af[3][2 + kk], Bh[kk], a3, 0, 0, 0);
      }

      const float tg = 1.0f - 2.0f * frcp(1.0f + Eg);
      const float si = frcp(1.0f + Ei);
      const float gf = sel4(a1, rho) + xgv[1];  // = -log2e * f
      const float go = sel4(a3, rho) + xgv[3];  // = -log2e * o
      const float sf = frcp(1.0f + fexp2(gf));
      c = sf * c + si * tg;
      const float tc = 1.0f - 2.0f * frcp(1.0f + fexp2(S2_ * c));
      const float so = frcp(1.0f + fexp2(go));
      const float hh = so * tc;
      u32 pk;
      asm("v_cvt_pk_bf16_f32 %0, %1, %2" : "=v"(pk) : "v"(hh), "v"(hh));
      hbuf[pn * (4 * HP_) + b * HP_ + w * 16 + q * 4 + rho] = (u16)pk;
      __syncthreads();
    }
  }

  // ---- head: final h is in hbuf[0]
  if (tid < 4 * FUT_) {
    const int bb = tid / FUT_;
    const int f = tid % FUT_;
    float a = blin[f];
#pragma unroll 8
    for (int k = 0; k < HL_; k++) a += b2f(hbuf[bb * HP_ + k]) * Wlin[f * HL_ + k];
    out[((size_t)(bg * 4 + bb) * NH_ + s) * FUT_ + f] = lrelu(a);
  }
}

extern "C" void kernel_launch(void* const* d_in, const int* in_sizes, int n_in,
                              void* d_out, int out_size, void* d_ws, size_t ws_size,
                              hipStream_t stream) {
  const float* dm = (const float*)d_in[0];
  const float* dh = (const float*)d_in[1];
  const int* eidx = (const int*)d_in[2];
  const float* Wroot = (const float*)d_in[3];
  const float* Wrel = (const float*)d_in[4];
  const float* bgnn = (const float*)d_in[5];
  const float* Wih = (const float*)d_in[6];
  const float* Whh = (const float*)d_in[7];
  const float* bih = (const float*)d_in[8];
  const float* bhh = (const float*)d_in[9];
  const float* Wlin = (const float*)d_in[10];
  const float* blin = (const float*)d_in[11];
  float* out = (float*)d_out;

  fused_kernel<<<256, 512, 0, stream>>>(dm, dh, eidx, Wroot, Wrel, bgnn, Wih, Whh,
                                        bih, bhh, Wlin, blin, out);
}